// Round 7
// baseline (269.823 us; speedup 1.0000x reference)
//
#include <hip/hip_runtime.h>
#include <math.h>

// B=4, T=2048, E=1024, H*D=1024; R = B*T = 8192.  K is always 1024.
#define R_ROWS 8192
#define T_SEQ  2048
#define E_DIM  1024
#define KC     32          // K/32 chunks for K=1024
#define KCR    256         // K/32 chunks for K=8192 (WT frag layout)
// Packed P storage: per batch, supertile P (128 rows) has 8 rowblocks x (4P+4)
// chunks; total chunks = sum_{P=0..15} 8*(4P+4) = 4352; each chunk = 512 elems.
#define PBATCH_ELEMS ((size_t)4352 * 512)

typedef __attribute__((ext_vector_type(8))) short short8;
typedef __attribute__((ext_vector_type(4))) float f32x4;

__device__ __forceinline__ ushort f2bf(float f) {
  uint u = __float_as_uint(f);
  u += 0x7FFFu + ((u >> 16) & 1u);   // round-to-nearest-even
  return (ushort)(u >> 16);
}
__device__ __forceinline__ float bf2f(ushort h) {
  return __uint_as_float(((uint)h) << 16);
}

// ---------------------------------------------------------------------------
// MFMA A/B fragment layout for a [R][K] bf16 matrix (KCx = K/32):
//   off(r,k) = (((r>>4)*KCx + (k>>5))*4 + ((k>>3)&3))*128 + (r&15)*8 + (k&7)
// ---------------------------------------------------------------------------

__device__ __forceinline__ void split_frag_unit(
    const float* __restrict__ in, ushort* __restrict__ hi,
    ushort* __restrict__ lo, int g)
{
  const int l = g & 15, h = (g >> 4) & 3;
  const int pq = g >> 6;
  const int q = pq & (KC - 1), p = pq >> 5;
  const size_t src = (size_t)(p * 16 + l) * 1024 + q * 32 + h * 8;
  const float4 v0 = *(const float4*)&in[src];
  const float4 v1 = *(const float4*)&in[src + 4];
  ushort hh[8], ll[8];
  const float v[8] = {v0.x, v0.y, v0.z, v0.w, v1.x, v1.y, v1.z, v1.w};
#pragma unroll
  for (int e = 0; e < 8; ++e) {
    hh[e] = f2bf(v[e]);
    ll[e] = f2bf(v[e] - bf2f(hh[e]));
  }
  *(uint4*)&hi[(size_t)g * 8] = *(const uint4*)hh;
  *(uint4*)&lo[(size_t)g * 8] = *(const uint4*)ll;
}

__device__ __forceinline__ void splitT_frag_unit(
    const float* __restrict__ in, ushort* __restrict__ hi,
    ushort* __restrict__ lo, int g)
{
  const int l = g & 15, h = (g >> 4) & 3;
  const int pq = g >> 6;
  const int q = pq & (KC - 1), p = pq >> 5;
  const int rr = p * 16 + l;          // logical row (k index of M's B-side)
  const int cc = q * 32 + h * 8;      // reduction col (e index)
  ushort hh[8], ll[8];
#pragma unroll
  for (int e = 0; e < 8; ++e) {
    const float v = in[(size_t)(cc + e) * 1024 + rr];
    hh[e] = f2bf(v);
    ll[e] = f2bf(v - bf2f(hh[e]));
  }
  *(uint4*)&hi[(size_t)g * 8] = *(const uint4*)hh;
  *(uint4*)&lo[(size_t)g * 8] = *(const uint4*)ll;
}

// ---------------------------------------------------------------------------
// ONE conversion launch: x (4096 blocks) + wo/wjv^T/wj (512 each), plus
// zeroing sc_raw and zsum (first 64 blocks).  Kills 3 launches + 1 memset.
// ---------------------------------------------------------------------------
__global__ __launch_bounds__(256) void cvt_all(
    const float* __restrict__ x, const float* __restrict__ wo,
    const float* __restrict__ wjv, const float* __restrict__ wj,
    ushort* __restrict__ xh, ushort* __restrict__ xl,
    ushort* __restrict__ woh, ushort* __restrict__ wol,
    ushort* __restrict__ wjvh, ushort* __restrict__ wjvl,
    ushort* __restrict__ wjh, ushort* __restrict__ wjl,
    float* __restrict__ sc_raw, float* __restrict__ zsum)
{
  const int blk = blockIdx.x;
  const int tid = threadIdx.x;
  if (blk < 64) {
    const int idx = blk * 256 + tid;          // 16384 = 2*R_ROWS floats
    if (idx < R_ROWS) sc_raw[idx] = 0.f;
    else              zsum[idx - R_ROWS] = 0.f;
  }
  if (blk < 4096) {
    split_frag_unit(x, xh, xl, blk * 256 + tid);
  } else if (blk < 4608) {
    split_frag_unit(wo, woh, wol, (blk - 4096) * 256 + tid);
  } else if (blk < 5120) {
    splitT_frag_unit(wjv, wjvh, wjvl, (blk - 4608) * 256 + tid);
  } else {
    split_frag_unit(wj, wjh, wjl, (blk - 5120) * 256 + tid);
  }
}

// ---------------------------------------------------------------------------
// Split-bf16 sc kernel, LDS-FREE K-loop (unchanged — at structure ceiling).
// ---------------------------------------------------------------------------
struct Frags { short8 ah[4], al[4], bh[4], bl[4]; };

__global__ __launch_bounds__(256, 2) void gemm_sq_direct(
    const ushort* __restrict__ xh, const ushort* __restrict__ xl,
    const ushort* __restrict__ wh, const ushort* __restrict__ wl,
    float* __restrict__ sc_raw)
{
  const int tid = threadIdx.x;
  const int m0 = blockIdx.y * 128, n0 = blockIdx.x * 128;
  const int wave = tid >> 6, lane = tid & 63;
  const int l15 = lane & 15, lq = lane >> 4;
  const int wm = (wave & 1) * 64, wn = (wave >> 1) * 64;

  size_t aoff[4], boff[4];
#pragma unroll
  for (int i = 0; i < 4; ++i)
    aoff[i] = ((size_t)(((m0 + wm) >> 4) + i) * KC * 4 + lq) * 128 + l15 * 8;
#pragma unroll
  for (int j = 0; j < 4; ++j)
    boff[j] = ((size_t)(((n0 + wn) >> 4) + j) * KC * 4 + lq) * 128 + l15 * 8;

  f32x4 acc[4][4] = {};
  Frags f0, f1;

  auto load = [&](Frags& f, int q) {
    const size_t dq = (size_t)q * 512;
#pragma unroll
    for (int i = 0; i < 4; ++i) {
      f.ah[i] = *(const short8*)(xh + aoff[i] + dq);
      f.al[i] = *(const short8*)(xl + aoff[i] + dq);
    }
#pragma unroll
    for (int j = 0; j < 4; ++j) {
      f.bh[j] = *(const short8*)(wh + boff[j] + dq);
      f.bl[j] = *(const short8*)(wl + boff[j] + dq);
    }
  };
  auto step = [&](const Frags& f) {
#pragma unroll
    for (int i = 0; i < 4; ++i)
#pragma unroll
      for (int j = 0; j < 4; ++j) {
        acc[i][j] = __builtin_amdgcn_mfma_f32_16x16x32_bf16(f.ah[i], f.bh[j], acc[i][j], 0, 0, 0);
        acc[i][j] = __builtin_amdgcn_mfma_f32_16x16x32_bf16(f.ah[i], f.bl[j], acc[i][j], 0, 0, 0);
        acc[i][j] = __builtin_amdgcn_mfma_f32_16x16x32_bf16(f.al[i], f.bh[j], acc[i][j], 0, 0, 0);
      }
  };

  load(f0, 0);
#pragma unroll 1
  for (int q = 0; q < KC; q += 2) {
    load(f1, q + 1);
    step(f0);
    if (q + 2 < KC) load(f0, q + 2);
    step(f1);
  }

  __shared__ float red[128][33];
#pragma unroll
  for (int i = 0; i < 4; ++i)
#pragma unroll
    for (int r = 0; r < 4; ++r) {
      const int row = wm + i * 16 + lq * 4 + r;
      float s = 0.f;
#pragma unroll
      for (int j = 0; j < 4; ++j) s += acc[i][j][r] * acc[i][j][r];
      red[row][(l15 << 1) | (wave >> 1)] = s;
    }
  __syncthreads();
  if (tid < 128) {
    float s = 0.f;
#pragma unroll
    for (int c = 0; c < 32; ++c) s += red[tid][c];
    atomicAdd(&sc_raw[m0 + tid], s);
  }
}

// ---------------------------------------------------------------------------
// M = wo @ wjv, split-precision direct-frag GEMM.  64x64 tiles, 256 blocks.
// Output: bf16 M in A-FRAG layout [f][k] (KC=32).  (unchanged)
// ---------------------------------------------------------------------------
struct Frags2 { short8 ah[2], al[2], bh[2], bl[2]; };

__global__ __launch_bounds__(256, 2) void gemm_m_split(
    const ushort* __restrict__ ah_, const ushort* __restrict__ al_,
    const ushort* __restrict__ bh_, const ushort* __restrict__ bl_,
    ushort* __restrict__ Mf)
{
  const int tid = threadIdx.x;
  const int m0 = blockIdx.y * 64, n0 = blockIdx.x * 64;
  const int wave = tid >> 6, lane = tid & 63;
  const int l15 = lane & 15, lq = lane >> 4;
  const int wm = (wave & 1) * 32, wn = (wave >> 1) * 32;

  size_t aoff[2], boff[2];
#pragma unroll
  for (int i = 0; i < 2; ++i)
    aoff[i] = ((size_t)(((m0 + wm) >> 4) + i) * KC * 4 + lq) * 128 + l15 * 8;
#pragma unroll
  for (int j = 0; j < 2; ++j)
    boff[j] = ((size_t)(((n0 + wn) >> 4) + j) * KC * 4 + lq) * 128 + l15 * 8;

  f32x4 acc[2][2] = {};
  Frags2 f0, f1;

  auto load = [&](Frags2& f, int q) {
    const size_t dq = (size_t)q * 512;
#pragma unroll
    for (int i = 0; i < 2; ++i) {
      f.ah[i] = *(const short8*)(ah_ + aoff[i] + dq);
      f.al[i] = *(const short8*)(al_ + aoff[i] + dq);
    }
#pragma unroll
    for (int j = 0; j < 2; ++j) {
      f.bh[j] = *(const short8*)(bh_ + boff[j] + dq);
      f.bl[j] = *(const short8*)(bl_ + boff[j] + dq);
    }
  };
  auto step = [&](const Frags2& f) {
#pragma unroll
    for (int i = 0; i < 2; ++i)
#pragma unroll
      for (int j = 0; j < 2; ++j) {
        acc[i][j] = __builtin_amdgcn_mfma_f32_16x16x32_bf16(f.ah[i], f.bh[j], acc[i][j], 0, 0, 0);
        acc[i][j] = __builtin_amdgcn_mfma_f32_16x16x32_bf16(f.ah[i], f.bl[j], acc[i][j], 0, 0, 0);
        acc[i][j] = __builtin_amdgcn_mfma_f32_16x16x32_bf16(f.al[i], f.bh[j], acc[i][j], 0, 0, 0);
      }
  };

  load(f0, 0);
#pragma unroll 1
  for (int q = 0; q < KC; q += 2) {
    load(f1, q + 1);
    step(f0);
    if (q + 2 < KC) load(f0, q + 2);
    step(f1);
  }

#pragma unroll
  for (int i = 0; i < 2; ++i)
#pragma unroll
    for (int j = 0; j < 2; ++j) {
      const int fb = m0 + wm + i * 16 + lq * 4;
      const int k  = n0 + wn + j * 16 + l15;
#pragma unroll
      for (int r = 0; r < 4; ++r) {
        const int f = fb + r;
        const size_t addr =
            (((size_t)(f >> 4) * KC + (k >> 5)) * 4 + ((k >> 3) & 3)) * 128 +
            (f & 15) * 8 + (k & 7);
        Mf[addr] = f2bf(acc[i][j][r]);
      }
    }
}

// ---------------------------------------------------------------------------
// P generation + prefix-max + softmax denominator, ONE kernel.
// Each block: load sc_raw -> scs (scaled), LDS prefix-max scan, then two
// paired supertiles (15-y, y): write bf16 P frags and atomicAdd fp32 row
// sums into zsum.  Replaces scan_max + zgen + pgen (3 launches -> 1).
// ---------------------------------------------------------------------------
__global__ __launch_bounds__(512) void pgen2(
    const float* __restrict__ sc_raw, ushort* __restrict__ P012,
    ushort* __restrict__ P3, float* __restrict__ zsum)
{
  const int y = blockIdx.x, b = blockIdx.y, zslice = blockIdx.z;
  const int bT = b * T_SEQ;
  ushort* pb = (b < 3) ? P012 + (size_t)b * PBATCH_ELEMS : P3;
  __shared__ float scs[T_SEQ];
  __shared__ float pma[T_SEQ];
  __shared__ float pmb[T_SEQ];
  const int tid = threadIdx.x;
  for (int i = tid; i < T_SEQ; i += 512) {
    const float v = sc_raw[bT + i] * 0.03125f;
    scs[i] = v;
    pma[i] = v;
  }
  __syncthreads();
  float* src = pma; float* dst = pmb;
  for (int off = 1; off < T_SEQ; off <<= 1) {
    for (int i = tid; i < T_SEQ; i += 512)
      dst[i] = (i >= off) ? fmaxf(src[i], src[i - off]) : src[i];
    __syncthreads();
    float* t = src; src = dst; dst = t;
  }
  const float* pms = src;   // inclusive prefix max

  const int lane = tid & 63;
  const int hi = lane >> 4, l = lane & 15;

#pragma unroll 1
  for (int ph = 0; ph < 2; ++ph) {
    const int P = ph ? y : 15 - y;
    const int W = 4 * P + 4;
    ushort* base = pb + (size_t)(16 * P * (P + 1)) * 512;
    const int nu = 512 * W;   // 16B units in this supertile
#pragma unroll 1
    for (int u = tid + zslice * 512; u < nu; u += 2048) {
      const int pr = (u >> 6) & 7, q = u >> 9;
      const int t = P * 128 + pr * 16 + l;
      const int s0 = q * 32 + hi * 8;
      const float st = scs[t], pm = pms[t];
      ushort tmp[8];
      float z = 0.f;
#pragma unroll
      for (int e = 0; e < 8; ++e) {
        const int s = s0 + e;
        float pe = 0.f;
        if (s <= t) pe = __expf(st * (scs[s] - pm));
        tmp[e] = f2bf(pe);
        z += pe;
      }
      *(uint4*)&base[(size_t)(pr * W + q) * 512 + hi * 128 + l * 8] =
          *(const uint4*)tmp;
      // reduce the 4 hi-lanes that share row t, one atomic per row
      z += __shfl_xor(z, 16);
      z += __shfl_xor(z, 32);
      if (hi == 0) atomicAdd(&zsum[bT + t], z);
    }
  }
}

// ---------------------------------------------------------------------------
// WT[f][rg] = sum_k M[f][k]*x[rg][k], direct frag both sides (unchanged).
// ---------------------------------------------------------------------------
struct FragsP { short8 a[4], b[4]; };

__global__ __launch_bounds__(256, 2) void gemm_wt(
    const ushort* __restrict__ Af, const ushort* __restrict__ Bf,
    ushort* __restrict__ WT)
{
  const int tid = threadIdx.x;
  const int m0 = blockIdx.y * 128, n0 = blockIdx.x * 128;
  const int wave = tid >> 6, lane = tid & 63;
  const int l15 = lane & 15, lq = lane >> 4;
  const int wm = (wave & 1) * 64, wn = (wave >> 1) * 64;

  size_t aoff[4], boff[4];
#pragma unroll
  for (int i = 0; i < 4; ++i)
    aoff[i] = ((size_t)(((m0 + wm) >> 4) + i) * KC * 4 + lq) * 128 + l15 * 8;
#pragma unroll
  for (int j = 0; j < 4; ++j)
    boff[j] = ((size_t)(((n0 + wn) >> 4) + j) * KC * 4 + lq) * 128 + l15 * 8;

  f32x4 acc[4][4] = {};
  FragsP f0, f1;

  auto load = [&](FragsP& f, int q) {
    const size_t dq = (size_t)q * 512;
#pragma unroll
    for (int i = 0; i < 4; ++i) f.a[i] = *(const short8*)(Af + aoff[i] + dq);
#pragma unroll
    for (int j = 0; j < 4; ++j) f.b[j] = *(const short8*)(Bf + boff[j] + dq);
  };
  auto step = [&](const FragsP& f) {
#pragma unroll
    for (int i = 0; i < 4; ++i)
#pragma unroll
      for (int j = 0; j < 4; ++j)
        acc[i][j] = __builtin_amdgcn_mfma_f32_16x16x32_bf16(f.a[i], f.b[j], acc[i][j], 0, 0, 0);
  };

  load(f0, 0);
#pragma unroll 1
  for (int q = 0; q < KC; q += 2) {
    load(f1, q + 1);
    step(f0);
    if (q + 2 < KC) load(f0, q + 2);
    step(f1);
  }

#pragma unroll
  for (int i = 0; i < 4; ++i)
#pragma unroll
    for (int j = 0; j < 4; ++j) {
      const int eb = m0 + wm + i * 16 + lq * 4;
      const int rg = n0 + wn + j * 16 + l15;
#pragma unroll
      for (int r = 0; r < 4; ++r) {
        const int e = eb + r;
        const size_t addr =
            (((size_t)(e >> 4) * KCR + (rg >> 5)) * 4 + ((rg >> 3) & 3)) * 128 +
            (e & 15) * 8 + (rg & 7);
        WT[addr] = f2bf(acc[i][j][r]);
      }
    }
}

// ---------------------------------------------------------------------------
// Attention GEMM: one supertile per 256-thread block (512 blocks -> 2/CU),
// waves 2t x 2e, acc[4][4] = 16 MFMA : 8 loads per chunk (2:1, was 8:6).
// Heavy supertiles dispatch first (ty = 15 - blockIdx.y).
//   out[t][e] = (1/zsum[t]) * sum_s P[t][s] * W[s][e]
// ---------------------------------------------------------------------------
__global__ __launch_bounds__(256, 2) void attn_gemm(
    const ushort* __restrict__ P012, const ushort* __restrict__ P3,
    const ushort* __restrict__ WT, const float* __restrict__ zsum,
    float* __restrict__ outp)
{
  const int b = blockIdx.z;
  const int ty = 15 - (int)blockIdx.y;
  const int e0 = blockIdx.x * 128;
  const int bT = b * T_SEQ;
  const ushort* pb = (b < 3) ? P012 + (size_t)b * PBATCH_ELEMS : P3;
  const int tid = threadIdx.x;
  const int wave = tid >> 6, lane = tid & 63;
  const int l15 = lane & 15, lq = lane >> 4;
  const int wm = (wave & 1) * 64;       // t-offset within 128
  const int wn = (wave >> 1) * 64;      // e-offset within 128
  const int W = 4 * ty + 4;
  const int t0 = ty * 128;

  size_t aoff[4], boff[4];
#pragma unroll
  for (int i = 0; i < 4; ++i)
    aoff[i] = ((size_t)(16 * ty * (ty + 1)) + (size_t)((wm >> 4) + i) * W) * 512
              + lq * 128 + l15 * 8;
#pragma unroll
  for (int j = 0; j < 4; ++j)
    boff[j] = ((size_t)((((e0 + wn) >> 4) + j) * KCR + (bT >> 5)) * 4 + lq) * 128
              + l15 * 8;

  f32x4 acc[4][4] = {};
  FragsP f0, f1;

  auto load = [&](FragsP& f, int q) {
    const size_t dq = (size_t)q * 512;
#pragma unroll
    for (int i = 0; i < 4; ++i) f.a[i] = *(const short8*)(pb + aoff[i] + dq);
#pragma unroll
    for (int j = 0; j < 4; ++j) f.b[j] = *(const short8*)(WT + boff[j] + dq);
  };
  auto step = [&](const FragsP& f) {
#pragma unroll
    for (int i = 0; i < 4; ++i)
#pragma unroll
      for (int j = 0; j < 4; ++j)
        acc[i][j] = __builtin_amdgcn_mfma_f32_16x16x32_bf16(f.a[i], f.b[j], acc[i][j], 0, 0, 0);
  };

  load(f0, 0);
#pragma unroll 1
  for (int q = 0; q < W; q += 2) {   // W is a multiple of 4
    load(f1, q + 1);
    step(f0);
    if (q + 2 < W) load(f0, q + 2);
    step(f1);
  }

  // Epilogue: scale by 1/zsum, write fp32 final output.
#pragma unroll
  for (int i = 0; i < 4; ++i)
#pragma unroll
    for (int r = 0; r < 4; ++r) {
      const int row = t0 + wm + i * 16 + lq * 4 + r;
      const float zi = 1.0f / zsum[bT + row];
#pragma unroll
      for (int j = 0; j < 4; ++j) {
        const int nb = e0 + wn + j * 16 + l15;
        outp[(size_t)(bT + row) * E_DIM + nb] = acc[i][j][r] * zi;
      }
    }
}

// ---------------------------------------------------------------------------
extern "C" void kernel_launch(void* const* d_in, const int* in_sizes, int n_in,
                              void* d_out, int out_size, void* d_ws, size_t ws_size,
                              hipStream_t stream) {
  (void)in_sizes; (void)n_in; (void)out_size; (void)ws_size;
  const float* x   = (const float*)d_in[0];
  const float* wj  = (const float*)d_in[1];
  const float* wjv = (const float*)d_in[2];
  const float* wo  = (const float*)d_in[3];
  float* out = (float*)d_out;

  ushort* xh_f  = (ushort*)d_ws;                        // 16.8 MB; later P(b0..2)
  ushort* xl_f  = xh_f  + (size_t)R_ROWS * E_DIM;       // 16.8 MB; later WT
  ushort* woh   = xl_f  + (size_t)R_ROWS * E_DIM;       // 2 MB, dead after gemm_m
  ushort* wol   = woh   + (size_t)E_DIM * E_DIM;        // 2 MB, dead after gemm_m
  ushort* wjvh  = wol   + (size_t)E_DIM * E_DIM;        // 2 MB, dead after gemm_m
  ushort* wjvl  = wjvh  + (size_t)E_DIM * E_DIM;        // 2 MB, dead after gemm_m
  ushort* wjh   = wjvl  + (size_t)E_DIM * E_DIM;        // 2 MB, dead after gemm_sq
  ushort* wjl   = wjh   + (size_t)E_DIM * E_DIM;        // 2 MB, dead after gemm_sq
  ushort* Mf    = wjl   + (size_t)E_DIM * E_DIM;        // 2 MB: bf16 M frags
  float* sc_raw = (float*)(Mf + (size_t)E_DIM * E_DIM);
  float* zsum   = sc_raw + R_ROWS;
  ushort* WT    = xl_f;     // xl_f dead after gemm_sq_direct (stream-serial)
  ushort* P012  = xh_f;     // xh_f dead after gemm_wt (3 x 4.46 MB <= 16.8 MB)
  ushort* P3    = woh;      // woh..wjl (12 MB) dead after gemm_sq/gemm_m

  // 1) all conversions + zero sc_raw/zsum (one launch)
  cvt_all<<<5632, 256, 0, stream>>>(x, wo, wjv, wj,
                                    xh_f, xl_f, woh, wol, wjvh, wjvl, wjh, wjl,
                                    sc_raw, zsum);

  // 2) M = wo @ wjv (split precision), bf16 frag-layout output
  gemm_m_split<<<dim3(E_DIM/64, E_DIM/64), 256, 0, stream>>>(
      woh, wol, wjvh, wjvl, Mf);

  // 3) sc_raw[r] = ||x_r @ wj^T||^2
  gemm_sq_direct<<<dim3(E_DIM/128, R_ROWS/128), 256, 0, stream>>>(
      xh_f, xl_f, wjh, wjl, sc_raw);

  // 4) WT[f][rg] = sum_k M[f][k]*x[rg][k]  (frag-layout output)
  gemm_wt<<<dim3(R_ROWS/128, E_DIM/128), 256, 0, stream>>>(Mf, xh_f, WT);

  // 5) P (packed frags) + prefix-max + zsum, one launch
  pgen2<<<dim3(8, 4, 4), 512, 0, stream>>>(sc_raw, P012, P3, zsum);

  // 6) out[t][e] = zinv[t] * sum_s P[t][s] * W[s][e]
  attn_gemm<<<dim3(E_DIM/128, 16, 4), 256, 0, stream>>>(P012, P3, WT, zsum, out);
}

// Round 11
// 263.760 us; speedup vs baseline: 1.0230x; 1.0230x over previous
//
#include <hip/hip_runtime.h>
#include <math.h>

// B=4, T=2048, E=1024, H*D=1024; R = B*T = 8192.  K is always 1024.
#define R_ROWS 8192
#define T_SEQ  2048
#define E_DIM  1024
#define KC     32          // K/32 chunks for K=1024
#define KCR    256         // K/32 chunks for K=8192 (WT frag layout)
// Packed P storage: per batch, supertile P (128 rows) has 8 rowblocks x (4P+4)
// chunks; total chunks = sum_{P=0..15} 8*(4P+4) = 4352; each chunk = 512 elems.
#define PBATCH_ELEMS ((size_t)4352 * 512)

typedef __attribute__((ext_vector_type(8))) short short8;
typedef __attribute__((ext_vector_type(4))) float f32x4;

__device__ __forceinline__ ushort f2bf(float f) {
  uint u = __float_as_uint(f);
  u += 0x7FFFu + ((u >> 16) & 1u);   // round-to-nearest-even
  return (ushort)(u >> 16);
}
__device__ __forceinline__ float bf2f(ushort h) {
  return __uint_as_float(((uint)h) << 16);
}

// ---------------------------------------------------------------------------
// MFMA A/B fragment layout for a [R][K] bf16 matrix (KCx = K/32):
//   off(r,k) = (((r>>4)*KCx + (k>>5))*4 + ((k>>3)&3))*128 + (r&15)*8 + (k&7)
// ---------------------------------------------------------------------------

__device__ __forceinline__ void split_frag_unit(
    const float* __restrict__ in, ushort* __restrict__ hi,
    ushort* __restrict__ lo, int g)
{
  const int l = g & 15, h = (g >> 4) & 3;
  const int pq = g >> 6;
  const int q = pq & (KC - 1), p = pq >> 5;
  const size_t src = (size_t)(p * 16 + l) * 1024 + q * 32 + h * 8;
  const float4 v0 = *(const float4*)&in[src];
  const float4 v1 = *(const float4*)&in[src + 4];
  ushort hh[8], ll[8];
  const float v[8] = {v0.x, v0.y, v0.z, v0.w, v1.x, v1.y, v1.z, v1.w};
#pragma unroll
  for (int e = 0; e < 8; ++e) {
    hh[e] = f2bf(v[e]);
    ll[e] = f2bf(v[e] - bf2f(hh[e]));
  }
  *(uint4*)&hi[(size_t)g * 8] = *(const uint4*)hh;
  *(uint4*)&lo[(size_t)g * 8] = *(const uint4*)ll;
}

__device__ __forceinline__ void splitT_frag_unit(
    const float* __restrict__ in, ushort* __restrict__ hi,
    ushort* __restrict__ lo, int g)
{
  const int l = g & 15, h = (g >> 4) & 3;
  const int pq = g >> 6;
  const int q = pq & (KC - 1), p = pq >> 5;
  const int rr = p * 16 + l;          // logical row (k index of M's B-side)
  const int cc = q * 32 + h * 8;      // reduction col (e index)
  ushort hh[8], ll[8];
#pragma unroll
  for (int e = 0; e < 8; ++e) {
    const float v = in[(size_t)(cc + e) * 1024 + rr];
    hh[e] = f2bf(v);
    ll[e] = f2bf(v - bf2f(hh[e]));
  }
  *(uint4*)&hi[(size_t)g * 8] = *(const uint4*)hh;
  *(uint4*)&lo[(size_t)g * 8] = *(const uint4*)ll;
}

// ---------------------------------------------------------------------------
// ONE conversion launch: x (4096 blocks) + wo/wjv^T/wj (512 each), plus
// zeroing sc_raw and zsum (first 64 blocks).
// ---------------------------------------------------------------------------
__global__ __launch_bounds__(256) void cvt_all(
    const float* __restrict__ x, const float* __restrict__ wo,
    const float* __restrict__ wjv, const float* __restrict__ wj,
    ushort* __restrict__ xh, ushort* __restrict__ xl,
    ushort* __restrict__ woh, ushort* __restrict__ wol,
    ushort* __restrict__ wjvh, ushort* __restrict__ wjvl,
    ushort* __restrict__ wjh, ushort* __restrict__ wjl,
    float* __restrict__ sc_raw, float* __restrict__ zsum)
{
  const int blk = blockIdx.x;
  const int tid = threadIdx.x;
  if (blk < 64) {
    const int idx = blk * 256 + tid;          // 16384 = 2*R_ROWS floats
    if (idx < R_ROWS) sc_raw[idx] = 0.f;
    else              zsum[idx - R_ROWS] = 0.f;
  }
  if (blk < 4096) {
    split_frag_unit(x, xh, xl, blk * 256 + tid);
  } else if (blk < 4608) {
    split_frag_unit(wo, woh, wol, (blk - 4096) * 256 + tid);
  } else if (blk < 5120) {
    splitT_frag_unit(wjv, wjvh, wjvl, (blk - 4608) * 256 + tid);
  } else {
    split_frag_unit(wj, wjh, wjl, (blk - 5120) * 256 + tid);
  }
}

// ---------------------------------------------------------------------------
// Split-bf16 sc kernel, LDS-FREE K-loop (unchanged — at structure ceiling).
// ---------------------------------------------------------------------------
struct Frags { short8 ah[4], al[4], bh[4], bl[4]; };

__global__ __launch_bounds__(256, 2) void gemm_sq_direct(
    const ushort* __restrict__ xh, const ushort* __restrict__ xl,
    const ushort* __restrict__ wh, const ushort* __restrict__ wl,
    float* __restrict__ sc_raw)
{
  const int tid = threadIdx.x;
  const int m0 = blockIdx.y * 128, n0 = blockIdx.x * 128;
  const int wave = tid >> 6, lane = tid & 63;
  const int l15 = lane & 15, lq = lane >> 4;
  const int wm = (wave & 1) * 64, wn = (wave >> 1) * 64;

  size_t aoff[4], boff[4];
#pragma unroll
  for (int i = 0; i < 4; ++i)
    aoff[i] = ((size_t)(((m0 + wm) >> 4) + i) * KC * 4 + lq) * 128 + l15 * 8;
#pragma unroll
  for (int j = 0; j < 4; ++j)
    boff[j] = ((size_t)(((n0 + wn) >> 4) + j) * KC * 4 + lq) * 128 + l15 * 8;

  f32x4 acc[4][4] = {};
  Frags f0, f1;

  auto load = [&](Frags& f, int q) {
    const size_t dq = (size_t)q * 512;
#pragma unroll
    for (int i = 0; i < 4; ++i) {
      f.ah[i] = *(const short8*)(xh + aoff[i] + dq);
      f.al[i] = *(const short8*)(xl + aoff[i] + dq);
    }
#pragma unroll
    for (int j = 0; j < 4; ++j) {
      f.bh[j] = *(const short8*)(wh + boff[j] + dq);
      f.bl[j] = *(const short8*)(wl + boff[j] + dq);
    }
  };
  auto step = [&](const Frags& f) {
#pragma unroll
    for (int i = 0; i < 4; ++i)
#pragma unroll
      for (int j = 0; j < 4; ++j) {
        acc[i][j] = __builtin_amdgcn_mfma_f32_16x16x32_bf16(f.ah[i], f.bh[j], acc[i][j], 0, 0, 0);
        acc[i][j] = __builtin_amdgcn_mfma_f32_16x16x32_bf16(f.ah[i], f.bl[j], acc[i][j], 0, 0, 0);
        acc[i][j] = __builtin_amdgcn_mfma_f32_16x16x32_bf16(f.al[i], f.bh[j], acc[i][j], 0, 0, 0);
      }
  };

  load(f0, 0);
#pragma unroll 1
  for (int q = 0; q < KC; q += 2) {
    load(f1, q + 1);
    step(f0);
    if (q + 2 < KC) load(f0, q + 2);
    step(f1);
  }

  __shared__ float red[128][33];
#pragma unroll
  for (int i = 0; i < 4; ++i)
#pragma unroll
    for (int r = 0; r < 4; ++r) {
      const int row = wm + i * 16 + lq * 4 + r;
      float s = 0.f;
#pragma unroll
      for (int j = 0; j < 4; ++j) s += acc[i][j][r] * acc[i][j][r];
      red[row][(l15 << 1) | (wave >> 1)] = s;
    }
  __syncthreads();
  if (tid < 128) {
    float s = 0.f;
#pragma unroll
    for (int c = 0; c < 32; ++c) s += red[tid][c];
    atomicAdd(&sc_raw[m0 + tid], s);
  }
}

// ---------------------------------------------------------------------------
// M = wo @ wjv, split-precision direct-frag GEMM.  64x64 tiles, 256 blocks.
// Output: bf16 M in A-FRAG layout [f][k] (KC=32).  (unchanged)
// ---------------------------------------------------------------------------
struct Frags2 { short8 ah[2], al[2], bh[2], bl[2]; };

__global__ __launch_bounds__(256, 2) void gemm_m_split(
    const ushort* __restrict__ ah_, const ushort* __restrict__ al_,
    const ushort* __restrict__ bh_, const ushort* __restrict__ bl_,
    ushort* __restrict__ Mf)
{
  const int tid = threadIdx.x;
  const int m0 = blockIdx.y * 64, n0 = blockIdx.x * 64;
  const int wave = tid >> 6, lane = tid & 63;
  const int l15 = lane & 15, lq = lane >> 4;
  const int wm = (wave & 1) * 32, wn = (wave >> 1) * 32;

  size_t aoff[2], boff[2];
#pragma unroll
  for (int i = 0; i < 2; ++i)
    aoff[i] = ((size_t)(((m0 + wm) >> 4) + i) * KC * 4 + lq) * 128 + l15 * 8;
#pragma unroll
  for (int j = 0; j < 2; ++j)
    boff[j] = ((size_t)(((n0 + wn) >> 4) + j) * KC * 4 + lq) * 128 + l15 * 8;

  f32x4 acc[2][2] = {};
  Frags2 f0, f1;

  auto load = [&](Frags2& f, int q) {
    const size_t dq = (size_t)q * 512;
#pragma unroll
    for (int i = 0; i < 2; ++i) {
      f.ah[i] = *(const short8*)(ah_ + aoff[i] + dq);
      f.al[i] = *(const short8*)(al_ + aoff[i] + dq);
    }
#pragma unroll
    for (int j = 0; j < 2; ++j) {
      f.bh[j] = *(const short8*)(bh_ + boff[j] + dq);
      f.bl[j] = *(const short8*)(bl_ + boff[j] + dq);
    }
  };
  auto step = [&](const Frags2& f) {
#pragma unroll
    for (int i = 0; i < 2; ++i)
#pragma unroll
      for (int j = 0; j < 2; ++j) {
        acc[i][j] = __builtin_amdgcn_mfma_f32_16x16x32_bf16(f.ah[i], f.bh[j], acc[i][j], 0, 0, 0);
        acc[i][j] = __builtin_amdgcn_mfma_f32_16x16x32_bf16(f.ah[i], f.bl[j], acc[i][j], 0, 0, 0);
        acc[i][j] = __builtin_amdgcn_mfma_f32_16x16x32_bf16(f.al[i], f.bh[j], acc[i][j], 0, 0, 0);
      }
  };

  load(f0, 0);
#pragma unroll 1
  for (int q = 0; q < KC; q += 2) {
    load(f1, q + 1);
    step(f0);
    if (q + 2 < KC) load(f0, q + 2);
    step(f1);
  }

#pragma unroll
  for (int i = 0; i < 2; ++i)
#pragma unroll
    for (int j = 0; j < 2; ++j) {
      const int fb = m0 + wm + i * 16 + lq * 4;
      const int k  = n0 + wn + j * 16 + l15;
#pragma unroll
      for (int r = 0; r < 4; ++r) {
        const int f = fb + r;
        const size_t addr =
            (((size_t)(f >> 4) * KC + (k >> 5)) * 4 + ((k >> 3) & 3)) * 128 +
            (f & 15) * 8 + (k & 7);
        Mf[addr] = f2bf(acc[i][j][r]);
      }
    }
}

// ---------------------------------------------------------------------------
// P generation + prefix-max + softmax denominator, ONE kernel.
// Grid (8, 4, 16) = 512 blocks (2/CU; was 128 = half the GPU idle).
// ---------------------------------------------------------------------------
__global__ __launch_bounds__(512) void pgen2(
    const float* __restrict__ sc_raw, ushort* __restrict__ P012,
    ushort* __restrict__ P3, float* __restrict__ zsum)
{
  const int y = blockIdx.x, b = blockIdx.y, zslice = blockIdx.z;
  const int bT = b * T_SEQ;
  ushort* pb = (b < 3) ? P012 + (size_t)b * PBATCH_ELEMS : P3;
  __shared__ float scs[T_SEQ];
  __shared__ float pma[T_SEQ];
  __shared__ float pmb[T_SEQ];
  const int tid = threadIdx.x;
  for (int i = tid; i < T_SEQ; i += 512) {
    const float v = sc_raw[bT + i] * 0.03125f;
    scs[i] = v;
    pma[i] = v;
  }
  __syncthreads();
  float* src = pma; float* dst = pmb;
  for (int off = 1; off < T_SEQ; off <<= 1) {
    for (int i = tid; i < T_SEQ; i += 512)
      dst[i] = (i >= off) ? fmaxf(src[i], src[i - off]) : src[i];
    __syncthreads();
    float* t = src; src = dst; dst = t;
  }
  const float* pms = src;   // inclusive prefix max

  const int lane = tid & 63;
  const int hi = lane >> 4, l = lane & 15;

#pragma unroll 1
  for (int ph = 0; ph < 2; ++ph) {
    const int P = ph ? y : 15 - y;
    const int W = 4 * P + 4;
    ushort* base = pb + (size_t)(16 * P * (P + 1)) * 512;
    const int nu = 512 * W;   // 16B units in this supertile
#pragma unroll 1
    for (int u = tid + zslice * 512; u < nu; u += 8192) {
      const int pr = (u >> 6) & 7, q = u >> 9;
      const int t = P * 128 + pr * 16 + l;
      const int s0 = q * 32 + hi * 8;
      const float st = scs[t], pm = pms[t];
      ushort tmp[8];
      float z = 0.f;
#pragma unroll
      for (int e = 0; e < 8; ++e) {
        const int s = s0 + e;
        float pe = 0.f;
        if (s <= t) pe = __expf(st * (scs[s] - pm));
        tmp[e] = f2bf(pe);
        z += pe;
      }
      *(uint4*)&base[(size_t)(pr * W + q) * 512 + hi * 128 + l * 8] =
          *(const uint4*)tmp;
      // reduce the 4 hi-lanes that share row t, one atomic per row
      z += __shfl_xor(z, 16);
      z += __shfl_xor(z, 32);
      if (hi == 0) atomicAdd(&zsum[bT + t], z);
    }
  }
}

// ---------------------------------------------------------------------------
// WT[f][rg] = sum_k M[f][k]*x[rg][k], direct frag both sides, now with
// 2-chunk double-buffering: 32 MFMA per 16-load prefetch unit (2x latency
// coverage vs round 7's 16:8-per-chunk depth-1).
// ---------------------------------------------------------------------------
struct FP2 { short8 a[2][4]; short8 b[2][4]; };

__global__ __launch_bounds__(256, 2) void gemm_wt(
    const ushort* __restrict__ Af, const ushort* __restrict__ Bf,
    ushort* __restrict__ WT)
{
  const int tid = threadIdx.x;
  const int m0 = blockIdx.y * 128, n0 = blockIdx.x * 128;
  const int wave = tid >> 6, lane = tid & 63;
  const int l15 = lane & 15, lq = lane >> 4;
  const int wm = (wave & 1) * 64, wn = (wave >> 1) * 64;

  size_t aoff[4], boff[4];
#pragma unroll
  for (int i = 0; i < 4; ++i)
    aoff[i] = ((size_t)(((m0 + wm) >> 4) + i) * KC * 4 + lq) * 128 + l15 * 8;
#pragma unroll
  for (int j = 0; j < 4; ++j)
    boff[j] = ((size_t)(((n0 + wn) >> 4) + j) * KC * 4 + lq) * 128 + l15 * 8;

  f32x4 acc[4][4] = {};
  FP2 f0, f1;

  auto load2 = [&](FP2& f, int q) {
#pragma unroll
    for (int c = 0; c < 2; ++c) {
      const size_t dq = (size_t)(q + c) * 512;
#pragma unroll
      for (int i = 0; i < 4; ++i) f.a[c][i] = *(const short8*)(Af + aoff[i] + dq);
#pragma unroll
      for (int j = 0; j < 4; ++j) f.b[c][j] = *(const short8*)(Bf + boff[j] + dq);
    }
  };
  auto step2 = [&](const FP2& f) {
#pragma unroll
    for (int c = 0; c < 2; ++c)
#pragma unroll
      for (int i = 0; i < 4; ++i)
#pragma unroll
        for (int j = 0; j < 4; ++j)
          acc[i][j] = __builtin_amdgcn_mfma_f32_16x16x32_bf16(f.a[c][i], f.b[c][j], acc[i][j], 0, 0, 0);
  };

  load2(f0, 0);
#pragma unroll 1
  for (int q = 0; q < KC; q += 4) {
    load2(f1, q + 2);
    step2(f0);
    if (q + 4 < KC) load2(f0, q + 4);
    step2(f1);
  }

#pragma unroll
  for (int i = 0; i < 4; ++i)
#pragma unroll
    for (int j = 0; j < 4; ++j) {
      const int eb = m0 + wm + i * 16 + lq * 4;
      const int rg = n0 + wn + j * 16 + l15;
#pragma unroll
      for (int r = 0; r < 4; ++r) {
        const int e = eb + r;
        const size_t addr =
            (((size_t)(e >> 4) * KCR + (rg >> 5)) * 4 + ((rg >> 3) & 3)) * 128 +
            (e & 15) * 8 + (rg & 7);
        WT[addr] = f2bf(acc[i][j][r]);
      }
    }
}

// ---------------------------------------------------------------------------
// Attention GEMM: paired supertiles (15-y, y) -> uniform 68 chunks/block
// (fixes round-7's all-resident imbalance), 512 thr / 8 waves (2t x 4e),
// wave = 64t x 32e, 2-chunk double-buffered prefetch (12 loads -> 16 MFMA).
//   out[t][e] = (1/zsum[t]) * sum_s P[t][s] * W[s][e]
// ---------------------------------------------------------------------------
struct FA2 { short8 a[2][4]; short8 b[2][2]; };

__global__ __launch_bounds__(512) void attn_gemm(
    const ushort* __restrict__ P012, const ushort* __restrict__ P3,
    const ushort* __restrict__ WT, const float* __restrict__ zsum,
    float* __restrict__ outp)
{
  const int b = blockIdx.z, y = blockIdx.y;
  const int e0 = blockIdx.x * 128;
  const int bT = b * T_SEQ;
  const ushort* pb = (b < 3) ? P012 + (size_t)b * PBATCH_ELEMS : P3;
  const int tid = threadIdx.x;
  const int wave = tid >> 6, lane = tid & 63;
  const int l15 = lane & 15, lq = lane >> 4;
  const int wm = (wave & 1) * 64;       // t-offset within 128
  const int wn = (wave >> 1) * 32;      // e-offset within 128

  size_t boff[2];
#pragma unroll
  for (int j = 0; j < 2; ++j)
    boff[j] = ((size_t)((((e0 + wn) >> 4) + j) * KCR + (bT >> 5)) * 4 + lq) * 128
              + l15 * 8;

#pragma unroll 1
  for (int ph = 0; ph < 2; ++ph) {
    const int ty = ph ? y : 15 - y;
    const int W = 4 * ty + 4;           // multiple of 4
    const int t0 = ty * 128;

    size_t aoff[4];
#pragma unroll
    for (int i = 0; i < 4; ++i)
      aoff[i] = ((size_t)(16 * ty * (ty + 1)) + (size_t)((wm >> 4) + i) * W) * 512
                + lq * 128 + l15 * 8;

    f32x4 acc[4][2] = {};
    FA2 f0, f1;

    auto load2 = [&](FA2& f, int q) {
#pragma unroll
      for (int c = 0; c < 2; ++c) {
        const size_t dq = (size_t)(q + c) * 512;
#pragma unroll
        for (int i = 0; i < 4; ++i) f.a[c][i] = *(const short8*)(pb + aoff[i] + dq);
#pragma unroll
        for (int j = 0; j < 2; ++j) f.b[c][j] = *(const short8*)(WT + boff[j] + dq);
      }
    };
    auto step2 = [&](const FA2& f) {
#pragma unroll
      for (int c = 0; c < 2; ++c)
#pragma unroll
        for (int i = 0; i < 4; ++i)
#pragma unroll
          for (int j = 0; j < 2; ++j)
            acc[i][j] = __builtin_amdgcn_mfma_f32_16x16x32_bf16(
                f.a[c][i], f.b[c][j], acc[i][j], 0, 0, 0);
    };

    load2(f0, 0);
#pragma unroll 1
    for (int q = 0; q < W; q += 4) {
      load2(f1, q + 2);
      step2(f0);
      if (q + 4 < W) load2(f0, q + 4);
      step2(f1);
    }

    // Epilogue: scale by 1/zsum, write fp32 final output.
#pragma unroll
    for (int i = 0; i < 4; ++i)
#pragma unroll
      for (int r = 0; r < 4; ++r) {
        const int row = t0 + wm + i * 16 + lq * 4 + r;
        const float zi = 1.0f / zsum[bT + row];
#pragma unroll
        for (int j = 0; j < 2; ++j) {
          const int nb = e0 + wn + j * 16 + l15;
          outp[(size_t)(bT + row) * E_DIM + nb] = acc[i][j][r] * zi;
        }
      }
  }
}

// ---------------------------------------------------------------------------
extern "C" void kernel_launch(void* const* d_in, const int* in_sizes, int n_in,
                              void* d_out, int out_size, void* d_ws, size_t ws_size,
                              hipStream_t stream) {
  (void)in_sizes; (void)n_in; (void)out_size; (void)ws_size;
  const float* x   = (const float*)d_in[0];
  const float* wj  = (const float*)d_in[1];
  const float* wjv = (const float*)d_in[2];
  const float* wo  = (const float*)d_in[3];
  float* out = (float*)d_out;

  ushort* xh_f  = (ushort*)d_ws;                        // 16.8 MB; later P(b0..2)
  ushort* xl_f  = xh_f  + (size_t)R_ROWS * E_DIM;       // 16.8 MB; later WT
  ushort* woh   = xl_f  + (size_t)R_ROWS * E_DIM;       // 2 MB, dead after gemm_m
  ushort* wol   = woh   + (size_t)E_DIM * E_DIM;        // 2 MB, dead after gemm_m
  ushort* wjvh  = wol   + (size_t)E_DIM * E_DIM;        // 2 MB, dead after gemm_m
  ushort* wjvl  = wjvh  + (size_t)E_DIM * E_DIM;        // 2 MB, dead after gemm_m
  ushort* wjh   = wjvl  + (size_t)E_DIM * E_DIM;        // 2 MB, dead after gemm_sq
  ushort* wjl   = wjh   + (size_t)E_DIM * E_DIM;        // 2 MB, dead after gemm_sq
  ushort* Mf    = wjl   + (size_t)E_DIM * E_DIM;        // 2 MB: bf16 M frags
  float* sc_raw = (float*)(Mf + (size_t)E_DIM * E_DIM);
  float* zsum   = sc_raw + R_ROWS;
  ushort* WT    = xl_f;     // xl_f dead after gemm_sq_direct (stream-serial)
  ushort* P012  = xh_f;     // xh_f dead after gemm_wt (3 x 4.46 MB <= 16.8 MB)
  ushort* P3    = woh;      // woh..wjl (12 MB) dead after gemm_sq/gemm_m

  // 1) all conversions + zero sc_raw/zsum (one launch)
  cvt_all<<<5632, 256, 0, stream>>>(x, wo, wjv, wj,
                                    xh_f, xl_f, woh, wol, wjvh, wjvl, wjh, wjl,
                                    sc_raw, zsum);

  // 2) M = wo @ wjv (split precision), bf16 frag-layout output
  gemm_m_split<<<dim3(E_DIM/64, E_DIM/64), 256, 0, stream>>>(
      woh, wol, wjvh, wjvl, Mf);

  // 3) sc_raw[r] = ||x_r @ wj^T||^2
  gemm_sq_direct<<<dim3(E_DIM/128, R_ROWS/128), 256, 0, stream>>>(
      xh_f, xl_f, wjh, wjl, sc_raw);

  // 4) WT[f][rg] = sum_k M[f][k]*x[rg][k]  (frag-layout output, 2-chunk dbuf)
  gemm_wt<<<dim3(R_ROWS/128, E_DIM/128), 256, 0, stream>>>(Mf, xh_f, WT);

  // 5) P (packed frags) + prefix-max + zsum, one launch, 512 blocks
  pgen2<<<dim3(8, 4, 16), 512, 0, stream>>>(sc_raw, P012, P3, zsum);

  // 6) out[t][e] = zinv[t] * sum_s P[t][s] * W[s][e]  (paired, 2-chunk dbuf)
  attn_gemm<<<dim3(E_DIM/128, 8, 4), 512, 0, stream>>>(P012, P3, WT, zsum, out);
}

// Round 12
// 243.840 us; speedup vs baseline: 1.1066x; 1.0817x over previous
//
#include <hip/hip_runtime.h>
#include <math.h>

// B=4, T=2048, E=1024, H*D=1024; R = B*T = 8192.  K is always 1024.
#define R_ROWS 8192
#define T_SEQ  2048
#define E_DIM  1024
#define KC     32          // K/32 chunks for K=1024
#define KCR    256         // K/32 chunks for K=8192 (WT frag layout)
// Packed P storage: per batch, supertile P (128 rows) has 8 rowblocks x (4P+4)
// chunks; total chunks = sum_{P=0..15} 8*(4P+4) = 4352; each chunk = 512 elems.
#define PBATCH_ELEMS ((size_t)4352 * 512)

typedef __attribute__((ext_vector_type(8))) short short8;
typedef __attribute__((ext_vector_type(4))) float f32x4;

__device__ __forceinline__ ushort f2bf(float f) {
  uint u = __float_as_uint(f);
  u += 0x7FFFu + ((u >> 16) & 1u);   // round-to-nearest-even
  return (ushort)(u >> 16);
}
__device__ __forceinline__ float bf2f(ushort h) {
  return __uint_as_float(((uint)h) << 16);
}

// ---------------------------------------------------------------------------
// MFMA A/B fragment layout for a [R][K] bf16 matrix (KCx = K/32):
//   off(r,k) = (((r>>4)*KCx + (k>>5))*4 + ((k>>3)&3))*128 + (r&15)*8 + (k&7)
// ---------------------------------------------------------------------------

__device__ __forceinline__ void split_frag_unit(
    const float* __restrict__ in, ushort* __restrict__ hi,
    ushort* __restrict__ lo, int g)
{
  const int l = g & 15, h = (g >> 4) & 3;
  const int pq = g >> 6;
  const int q = pq & (KC - 1), p = pq >> 5;
  const size_t src = (size_t)(p * 16 + l) * 1024 + q * 32 + h * 8;
  const float4 v0 = *(const float4*)&in[src];
  const float4 v1 = *(const float4*)&in[src + 4];
  ushort hh[8], ll[8];
  const float v[8] = {v0.x, v0.y, v0.z, v0.w, v1.x, v1.y, v1.z, v1.w};
#pragma unroll
  for (int e = 0; e < 8; ++e) {
    hh[e] = f2bf(v[e]);
    ll[e] = f2bf(v[e] - bf2f(hh[e]));
  }
  *(uint4*)&hi[(size_t)g * 8] = *(const uint4*)hh;
  *(uint4*)&lo[(size_t)g * 8] = *(const uint4*)ll;
}

__device__ __forceinline__ void splitT_frag_unit(
    const float* __restrict__ in, ushort* __restrict__ hi,
    ushort* __restrict__ lo, int g)
{
  const int l = g & 15, h = (g >> 4) & 3;
  const int pq = g >> 6;
  const int q = pq & (KC - 1), p = pq >> 5;
  const int rr = p * 16 + l;          // logical row (k index of M's B-side)
  const int cc = q * 32 + h * 8;      // reduction col (e index)
  ushort hh[8], ll[8];
#pragma unroll
  for (int e = 0; e < 8; ++e) {
    const float v = in[(size_t)(cc + e) * 1024 + rr];
    hh[e] = f2bf(v);
    ll[e] = f2bf(v - bf2f(hh[e]));
  }
  *(uint4*)&hi[(size_t)g * 8] = *(const uint4*)hh;
  *(uint4*)&lo[(size_t)g * 8] = *(const uint4*)ll;
}

// ---------------------------------------------------------------------------
// ONE conversion launch: x (4096 blocks) + wo/wjv^T/wj (512 each), plus
// zeroing sc_raw and zsum (first 64 blocks).
// ---------------------------------------------------------------------------
__global__ __launch_bounds__(256) void cvt_all(
    const float* __restrict__ x, const float* __restrict__ wo,
    const float* __restrict__ wjv, const float* __restrict__ wj,
    ushort* __restrict__ xh, ushort* __restrict__ xl,
    ushort* __restrict__ woh, ushort* __restrict__ wol,
    ushort* __restrict__ wjvh, ushort* __restrict__ wjvl,
    ushort* __restrict__ wjh, ushort* __restrict__ wjl,
    float* __restrict__ sc_raw, float* __restrict__ zsum)
{
  const int blk = blockIdx.x;
  const int tid = threadIdx.x;
  if (blk < 64) {
    const int idx = blk * 256 + tid;          // 16384 = 2*R_ROWS floats
    if (idx < R_ROWS) sc_raw[idx] = 0.f;
    else              zsum[idx - R_ROWS] = 0.f;
  }
  if (blk < 4096) {
    split_frag_unit(x, xh, xl, blk * 256 + tid);
  } else if (blk < 4608) {
    split_frag_unit(wo, woh, wol, (blk - 4096) * 256 + tid);
  } else if (blk < 5120) {
    splitT_frag_unit(wjv, wjvh, wjvl, (blk - 4608) * 256 + tid);
  } else {
    split_frag_unit(wj, wjh, wjl, (blk - 5120) * 256 + tid);
  }
}

// ---------------------------------------------------------------------------
// MERGED: gemm_sq (blocks 0..511) + gemm_m (blocks 512..767).  Independent
// work, both depend only on cvt_all -> one launch gap saved.
// ---------------------------------------------------------------------------
struct Frags { short8 ah[4], al[4], bh[4], bl[4]; };
struct Frags2 { short8 ah[2], al[2], bh[2], bl[2]; };

__global__ __launch_bounds__(256, 2) void gemm_sq_m(
    const ushort* __restrict__ xh, const ushort* __restrict__ xl,
    const ushort* __restrict__ wh, const ushort* __restrict__ wl,
    float* __restrict__ sc_raw,
    const ushort* __restrict__ ah_, const ushort* __restrict__ al_,
    const ushort* __restrict__ bh_, const ushort* __restrict__ bl_,
    ushort* __restrict__ Mf)
{
  const int blk = blockIdx.x;
  const int tid = threadIdx.x;
  const int wave = tid >> 6, lane = tid & 63;
  const int l15 = lane & 15, lq = lane >> 4;

  if (blk < 512) {
    // ---------------- gemm_sq path: sc_raw[r] = ||x_r @ wj^T||^2 ----------
    const int m0 = (blk >> 3) * 128, n0 = (blk & 7) * 128;
    const int wm = (wave & 1) * 64, wn = (wave >> 1) * 64;

    size_t aoff[4], boff[4];
#pragma unroll
    for (int i = 0; i < 4; ++i)
      aoff[i] = ((size_t)(((m0 + wm) >> 4) + i) * KC * 4 + lq) * 128 + l15 * 8;
#pragma unroll
    for (int j = 0; j < 4; ++j)
      boff[j] = ((size_t)(((n0 + wn) >> 4) + j) * KC * 4 + lq) * 128 + l15 * 8;

    f32x4 acc[4][4] = {};
    Frags f0, f1;

    auto load = [&](Frags& f, int q) {
      const size_t dq = (size_t)q * 512;
#pragma unroll
      for (int i = 0; i < 4; ++i) {
        f.ah[i] = *(const short8*)(xh + aoff[i] + dq);
        f.al[i] = *(const short8*)(xl + aoff[i] + dq);
      }
#pragma unroll
      for (int j = 0; j < 4; ++j) {
        f.bh[j] = *(const short8*)(wh + boff[j] + dq);
        f.bl[j] = *(const short8*)(wl + boff[j] + dq);
      }
    };
    auto step = [&](const Frags& f) {
#pragma unroll
      for (int i = 0; i < 4; ++i)
#pragma unroll
        for (int j = 0; j < 4; ++j) {
          acc[i][j] = __builtin_amdgcn_mfma_f32_16x16x32_bf16(f.ah[i], f.bh[j], acc[i][j], 0, 0, 0);
          acc[i][j] = __builtin_amdgcn_mfma_f32_16x16x32_bf16(f.ah[i], f.bl[j], acc[i][j], 0, 0, 0);
          acc[i][j] = __builtin_amdgcn_mfma_f32_16x16x32_bf16(f.al[i], f.bh[j], acc[i][j], 0, 0, 0);
        }
    };

    load(f0, 0);
#pragma unroll 1
    for (int q = 0; q < KC; q += 2) {
      load(f1, q + 1);
      step(f0);
      if (q + 2 < KC) load(f0, q + 2);
      step(f1);
    }

    __shared__ float red[128][33];
#pragma unroll
    for (int i = 0; i < 4; ++i)
#pragma unroll
      for (int r = 0; r < 4; ++r) {
        const int row = wm + i * 16 + lq * 4 + r;
        float s = 0.f;
#pragma unroll
        for (int j = 0; j < 4; ++j) s += acc[i][j][r] * acc[i][j][r];
        red[row][(l15 << 1) | (wave >> 1)] = s;
      }
    __syncthreads();
    if (tid < 128) {
      float s = 0.f;
#pragma unroll
      for (int c = 0; c < 32; ++c) s += red[tid][c];
      atomicAdd(&sc_raw[m0 + tid], s);
    }
  } else {
    // ---------------- gemm_m path: Mf = bf16(wo @ wjv) in frag layout ------
    const int mm = blk - 512;
    const int m0 = (mm >> 4) * 64, n0 = (mm & 15) * 64;
    const int wm = (wave & 1) * 32, wn = (wave >> 1) * 32;

    size_t aoff[2], boff[2];
#pragma unroll
    for (int i = 0; i < 2; ++i)
      aoff[i] = ((size_t)(((m0 + wm) >> 4) + i) * KC * 4 + lq) * 128 + l15 * 8;
#pragma unroll
    for (int j = 0; j < 2; ++j)
      boff[j] = ((size_t)(((n0 + wn) >> 4) + j) * KC * 4 + lq) * 128 + l15 * 8;

    f32x4 acc[2][2] = {};
    Frags2 f0, f1;

    auto load = [&](Frags2& f, int q) {
      const size_t dq = (size_t)q * 512;
#pragma unroll
      for (int i = 0; i < 2; ++i) {
        f.ah[i] = *(const short8*)(ah_ + aoff[i] + dq);
        f.al[i] = *(const short8*)(al_ + aoff[i] + dq);
      }
#pragma unroll
      for (int j = 0; j < 2; ++j) {
        f.bh[j] = *(const short8*)(bh_ + boff[j] + dq);
        f.bl[j] = *(const short8*)(bl_ + boff[j] + dq);
      }
    };
    auto step = [&](const Frags2& f) {
#pragma unroll
      for (int i = 0; i < 2; ++i)
#pragma unroll
        for (int j = 0; j < 2; ++j) {
          acc[i][j] = __builtin_amdgcn_mfma_f32_16x16x32_bf16(f.ah[i], f.bh[j], acc[i][j], 0, 0, 0);
          acc[i][j] = __builtin_amdgcn_mfma_f32_16x16x32_bf16(f.ah[i], f.bl[j], acc[i][j], 0, 0, 0);
          acc[i][j] = __builtin_amdgcn_mfma_f32_16x16x32_bf16(f.al[i], f.bh[j], acc[i][j], 0, 0, 0);
        }
    };

    load(f0, 0);
#pragma unroll 1
    for (int q = 0; q < KC; q += 2) {
      load(f1, q + 1);
      step(f0);
      if (q + 2 < KC) load(f0, q + 2);
      step(f1);
    }

#pragma unroll
    for (int i = 0; i < 2; ++i)
#pragma unroll
      for (int j = 0; j < 2; ++j) {
        const int fb = m0 + wm + i * 16 + lq * 4;
        const int k  = n0 + wn + j * 16 + l15;
#pragma unroll
        for (int r = 0; r < 4; ++r) {
          const int f = fb + r;
          const size_t addr =
              (((size_t)(f >> 4) * KC + (k >> 5)) * 4 + ((k >> 3) & 3)) * 128 +
              (f & 15) * 8 + (k & 7);
          Mf[addr] = f2bf(acc[i][j][r]);
        }
      }
  }
}

// ---------------------------------------------------------------------------
// P generation + prefix-max + softmax denominator, ONE kernel.
// Grid (8, 4, 16) = 512 blocks (2/CU).
// ---------------------------------------------------------------------------
__global__ __launch_bounds__(512) void pgen2(
    const float* __restrict__ sc_raw, ushort* __restrict__ P012,
    ushort* __restrict__ P3, float* __restrict__ zsum)
{
  const int y = blockIdx.x, b = blockIdx.y, zslice = blockIdx.z;
  const int bT = b * T_SEQ;
  ushort* pb = (b < 3) ? P012 + (size_t)b * PBATCH_ELEMS : P3;
  __shared__ float scs[T_SEQ];
  __shared__ float pma[T_SEQ];
  __shared__ float pmb[T_SEQ];
  const int tid = threadIdx.x;
  for (int i = tid; i < T_SEQ; i += 512) {
    const float v = sc_raw[bT + i] * 0.03125f;
    scs[i] = v;
    pma[i] = v;
  }
  __syncthreads();
  float* src = pma; float* dst = pmb;
  for (int off = 1; off < T_SEQ; off <<= 1) {
    for (int i = tid; i < T_SEQ; i += 512)
      dst[i] = (i >= off) ? fmaxf(src[i], src[i - off]) : src[i];
    __syncthreads();
    float* t = src; src = dst; dst = t;
  }
  const float* pms = src;   // inclusive prefix max

  const int lane = tid & 63;
  const int hi = lane >> 4, l = lane & 15;

#pragma unroll 1
  for (int ph = 0; ph < 2; ++ph) {
    const int P = ph ? y : 15 - y;
    const int W = 4 * P + 4;
    ushort* base = pb + (size_t)(16 * P * (P + 1)) * 512;
    const int nu = 512 * W;   // 16B units in this supertile
#pragma unroll 1
    for (int u = tid + zslice * 512; u < nu; u += 8192) {
      const int pr = (u >> 6) & 7, q = u >> 9;
      const int t = P * 128 + pr * 16 + l;
      const int s0 = q * 32 + hi * 8;
      const float st = scs[t], pm = pms[t];
      ushort tmp[8];
      float z = 0.f;
#pragma unroll
      for (int e = 0; e < 8; ++e) {
        const int s = s0 + e;
        float pe = 0.f;
        if (s <= t) pe = __expf(st * (scs[s] - pm));
        tmp[e] = f2bf(pe);
        z += pe;
      }
      *(uint4*)&base[(size_t)(pr * W + q) * 512 + hi * 128 + l * 8] =
          *(const uint4*)tmp;
      // reduce the 4 hi-lanes that share row t, one atomic per row
      z += __shfl_xor(z, 16);
      z += __shfl_xor(z, 32);
      if (hi == 0) atomicAdd(&zsum[bT + t], z);
    }
  }
}

// ---------------------------------------------------------------------------
// WT[f][rg] = sum_k M[f][k]*x[rg][k], 2-chunk double-buffer with
// sched_barrier(0) pinning the prefetch ISSUE before the MFMA cluster
// (round-11 PMC: VGPR=84 proved the compiler de-pipelined source dbuf).
// ---------------------------------------------------------------------------
struct FP2 { short8 a[2][4]; short8 b[2][4]; };

__global__ __launch_bounds__(256, 2) void gemm_wt(
    const ushort* __restrict__ Af, const ushort* __restrict__ Bf,
    ushort* __restrict__ WT)
{
  const int tid = threadIdx.x;
  const int m0 = blockIdx.y * 128, n0 = blockIdx.x * 128;
  const int wave = tid >> 6, lane = tid & 63;
  const int l15 = lane & 15, lq = lane >> 4;
  const int wm = (wave & 1) * 64, wn = (wave >> 1) * 64;

  size_t aoff[4], boff[4];
#pragma unroll
  for (int i = 0; i < 4; ++i)
    aoff[i] = ((size_t)(((m0 + wm) >> 4) + i) * KC * 4 + lq) * 128 + l15 * 8;
#pragma unroll
  for (int j = 0; j < 4; ++j)
    boff[j] = ((size_t)(((n0 + wn) >> 4) + j) * KC * 4 + lq) * 128 + l15 * 8;

  f32x4 acc[4][4] = {};
  FP2 f0, f1;

  auto load2 = [&](FP2& f, int q) {
#pragma unroll
    for (int c = 0; c < 2; ++c) {
      const size_t dq = (size_t)(q + c) * 512;
#pragma unroll
      for (int i = 0; i < 4; ++i) f.a[c][i] = *(const short8*)(Af + aoff[i] + dq);
#pragma unroll
      for (int j = 0; j < 4; ++j) f.b[c][j] = *(const short8*)(Bf + boff[j] + dq);
    }
  };
  auto step2 = [&](const FP2& f) {
#pragma unroll
    for (int c = 0; c < 2; ++c)
#pragma unroll
      for (int i = 0; i < 4; ++i)
#pragma unroll
        for (int j = 0; j < 4; ++j)
          acc[i][j] = __builtin_amdgcn_mfma_f32_16x16x32_bf16(f.a[c][i], f.b[c][j], acc[i][j], 0, 0, 0);
  };

  load2(f0, 0);
  __builtin_amdgcn_sched_barrier(0);
#pragma unroll 1
  for (int q = 0; q < KC; q += 4) {
    load2(f1, q + 2);
    __builtin_amdgcn_sched_barrier(0);   // f1 loads ISSUE before f0's MFMAs
    step2(f0);
    if (q + 4 < KC) {
      load2(f0, q + 4);
      __builtin_amdgcn_sched_barrier(0); // f0 loads ISSUE before f1's MFMAs
    }
    step2(f1);
  }

#pragma unroll
  for (int i = 0; i < 4; ++i)
#pragma unroll
    for (int j = 0; j < 4; ++j) {
      const int eb = m0 + wm + i * 16 + lq * 4;
      const int rg = n0 + wn + j * 16 + l15;
#pragma unroll
      for (int r = 0; r < 4; ++r) {
        const int e = eb + r;
        const size_t addr =
            (((size_t)(e >> 4) * KCR + (rg >> 5)) * 4 + ((rg >> 3) & 3)) * 128 +
            (e & 15) * 8 + (rg & 7);
        WT[addr] = f2bf(acc[i][j][r]);
      }
    }
}

// ---------------------------------------------------------------------------
// Attention GEMM: paired supertiles (15-y, y), 512 thr / 8 waves (2t x 4e),
// 2-chunk double-buffer with sched_barrier(0)-pinned prefetch issue.
//   out[t][e] = (1/zsum[t]) * sum_s P[t][s] * W[s][e]
// ---------------------------------------------------------------------------
struct FA2 { short8 a[2][4]; short8 b[2][2]; };

__global__ __launch_bounds__(512) void attn_gemm(
    const ushort* __restrict__ P012, const ushort* __restrict__ P3,
    const ushort* __restrict__ WT, const float* __restrict__ zsum,
    float* __restrict__ outp)
{
  const int b = blockIdx.z, y = blockIdx.y;
  const int e0 = blockIdx.x * 128;
  const int bT = b * T_SEQ;
  const ushort* pb = (b < 3) ? P012 + (size_t)b * PBATCH_ELEMS : P3;
  const int tid = threadIdx.x;
  const int wave = tid >> 6, lane = tid & 63;
  const int l15 = lane & 15, lq = lane >> 4;
  const int wm = (wave & 1) * 64;       // t-offset within 128
  const int wn = (wave >> 1) * 32;      // e-offset within 128

  size_t boff[2];
#pragma unroll
  for (int j = 0; j < 2; ++j)
    boff[j] = ((size_t)((((e0 + wn) >> 4) + j) * KCR + (bT >> 5)) * 4 + lq) * 128
              + l15 * 8;

#pragma unroll 1
  for (int ph = 0; ph < 2; ++ph) {
    const int ty = ph ? y : 15 - y;
    const int W = 4 * ty + 4;           // multiple of 4
    const int t0 = ty * 128;

    size_t aoff[4];
#pragma unroll
    for (int i = 0; i < 4; ++i)
      aoff[i] = ((size_t)(16 * ty * (ty + 1)) + (size_t)((wm >> 4) + i) * W) * 512
                + lq * 128 + l15 * 8;

    f32x4 acc[4][2] = {};
    FA2 f0, f1;

    auto load2 = [&](FA2& f, int q) {
#pragma unroll
      for (int c = 0; c < 2; ++c) {
        const size_t dq = (size_t)(q + c) * 512;
#pragma unroll
        for (int i = 0; i < 4; ++i) f.a[c][i] = *(const short8*)(pb + aoff[i] + dq);
#pragma unroll
        for (int j = 0; j < 2; ++j) f.b[c][j] = *(const short8*)(WT + boff[j] + dq);
      }
    };
    auto step2 = [&](const FA2& f) {
#pragma unroll
      for (int c = 0; c < 2; ++c)
#pragma unroll
        for (int i = 0; i < 4; ++i)
#pragma unroll
          for (int j = 0; j < 2; ++j)
            acc[i][j] = __builtin_amdgcn_mfma_f32_16x16x32_bf16(
                f.a[c][i], f.b[c][j], acc[i][j], 0, 0, 0);
    };

    load2(f0, 0);
    __builtin_amdgcn_sched_barrier(0);
#pragma unroll 1
    for (int q = 0; q < W; q += 4) {
      load2(f1, q + 2);
      __builtin_amdgcn_sched_barrier(0);   // pin f1 issue before f0 MFMAs
      step2(f0);
      if (q + 4 < W) {
        load2(f0, q + 4);
        __builtin_amdgcn_sched_barrier(0); // pin f0 issue before f1 MFMAs
      }
      step2(f1);
    }

    // Epilogue: scale by 1/zsum, write fp32 final output.
#pragma unroll
    for (int i = 0; i < 4; ++i)
#pragma unroll
      for (int r = 0; r < 4; ++r) {
        const int row = t0 + wm + i * 16 + lq * 4 + r;
        const float zi = 1.0f / zsum[bT + row];
#pragma unroll
        for (int j = 0; j < 2; ++j) {
          const int nb = e0 + wn + j * 16 + l15;
          outp[(size_t)(bT + row) * E_DIM + nb] = acc[i][j][r] * zi;
        }
      }
  }
}

// ---------------------------------------------------------------------------
extern "C" void kernel_launch(void* const* d_in, const int* in_sizes, int n_in,
                              void* d_out, int out_size, void* d_ws, size_t ws_size,
                              hipStream_t stream) {
  (void)in_sizes; (void)n_in; (void)out_size; (void)ws_size;
  const float* x   = (const float*)d_in[0];
  const float* wj  = (const float*)d_in[1];
  const float* wjv = (const float*)d_in[2];
  const float* wo  = (const float*)d_in[3];
  float* out = (float*)d_out;

  ushort* xh_f  = (ushort*)d_ws;                        // 16.8 MB; later P(b0..2)
  ushort* xl_f  = xh_f  + (size_t)R_ROWS * E_DIM;       // 16.8 MB; later WT
  ushort* woh   = xl_f  + (size_t)R_ROWS * E_DIM;       // 2 MB, dead after gemm_sq_m
  ushort* wol   = woh   + (size_t)E_DIM * E_DIM;        // 2 MB
  ushort* wjvh  = wol   + (size_t)E_DIM * E_DIM;        // 2 MB
  ushort* wjvl  = wjvh  + (size_t)E_DIM * E_DIM;        // 2 MB
  ushort* wjh   = wjvl  + (size_t)E_DIM * E_DIM;        // 2 MB
  ushort* wjl   = wjh   + (size_t)E_DIM * E_DIM;        // 2 MB
  ushort* Mf    = wjl   + (size_t)E_DIM * E_DIM;        // 2 MB: bf16 M frags
  float* sc_raw = (float*)(Mf + (size_t)E_DIM * E_DIM);
  float* zsum   = sc_raw + R_ROWS;
  ushort* WT    = xl_f;     // xl_f dead after gemm_sq_m (stream-serial)
  ushort* P012  = xh_f;     // xh_f dead after gemm_wt (3 x 4.46 MB <= 16.8 MB)
  ushort* P3    = woh;      // woh..wjl (12 MB) dead after gemm_sq_m

  // 1) all conversions + zero sc_raw/zsum (one launch)
  cvt_all<<<5632, 256, 0, stream>>>(x, wo, wjv, wj,
                                    xh_f, xl_f, woh, wol, wjvh, wjvl, wjh, wjl,
                                    sc_raw, zsum);

  // 2) MERGED: sc_raw[r] = ||x_r @ wj^T||^2  AND  Mf = bf16(wo @ wjv)
  gemm_sq_m<<<768, 256, 0, stream>>>(xh_f, xl_f, wjh, wjl, sc_raw,
                                     woh, wol, wjvh, wjvl, Mf);

  // 3) WT[f][rg] = sum_k M[f][k]*x[rg][k]  (sched_barrier-pinned prefetch)
  gemm_wt<<<dim3(R_ROWS/128, E_DIM/128), 256, 0, stream>>>(Mf, xh_f, WT);

  // 4) P (packed frags) + prefix-max + zsum
  pgen2<<<dim3(8, 4, 16), 512, 0, stream>>>(sc_raw, P012, P3, zsum);

  // 5) out[t][e] = zinv[t] * sum_s P[t][s] * W[s][e]  (pinned prefetch)
  attn_gemm<<<dim3(E_DIM/128, 8, 4), 512, 0, stream>>>(P012, P3, WT, zsum, out);
}

// Round 13
// 243.329 us; speedup vs baseline: 1.1089x; 1.0021x over previous
//
#include <hip/hip_runtime.h>
#include <math.h>

// B=4, T=2048, E=1024, H*D=1024; R = B*T = 8192.  K is always 1024.
#define R_ROWS 8192
#define T_SEQ  2048
#define E_DIM  1024
#define KC     32          // K/32 chunks for K=1024
#define KCR    256         // K/32 chunks for K=8192 (WT frag layout)
// Packed P storage: per batch, supertile P (128 rows) has 8 rowblocks x (4P+4)
// chunks; total chunks = sum_{P=0..15} 8*(4P+4) = 4352; each chunk = 512 elems.
#define PBATCH_ELEMS ((size_t)4352 * 512)

typedef __attribute__((ext_vector_type(8))) short short8;
typedef __attribute__((ext_vector_type(4))) float f32x4;

__device__ __forceinline__ ushort f2bf(float f) {
  uint u = __float_as_uint(f);
  u += 0x7FFFu + ((u >> 16) & 1u);   // round-to-nearest-even
  return (ushort)(u >> 16);
}
__device__ __forceinline__ float bf2f(ushort h) {
  return __uint_as_float(((uint)h) << 16);
}

// ---------------------------------------------------------------------------
// MFMA A/B fragment layout for a [R][K] bf16 matrix (KCx = K/32):
//   off(r,k) = (((r>>4)*KCx + (k>>5))*4 + ((k>>3)&3))*128 + (r&15)*8 + (k&7)
// ---------------------------------------------------------------------------

__device__ __forceinline__ void split_frag_unit(
    const float* __restrict__ in, ushort* __restrict__ hi,
    ushort* __restrict__ lo, int g)
{
  const int l = g & 15, h = (g >> 4) & 3;
  const int pq = g >> 6;
  const int q = pq & (KC - 1), p = pq >> 5;
  const size_t src = (size_t)(p * 16 + l) * 1024 + q * 32 + h * 8;
  const float4 v0 = *(const float4*)&in[src];
  const float4 v1 = *(const float4*)&in[src + 4];
  ushort hh[8], ll[8];
  const float v[8] = {v0.x, v0.y, v0.z, v0.w, v1.x, v1.y, v1.z, v1.w};
#pragma unroll
  for (int e = 0; e < 8; ++e) {
    hh[e] = f2bf(v[e]);
    ll[e] = f2bf(v[e] - bf2f(hh[e]));
  }
  *(uint4*)&hi[(size_t)g * 8] = *(const uint4*)hh;
  *(uint4*)&lo[(size_t)g * 8] = *(const uint4*)ll;
}

__device__ __forceinline__ void splitT_frag_unit(
    const float* __restrict__ in, ushort* __restrict__ hi,
    ushort* __restrict__ lo, int g)
{
  const int l = g & 15, h = (g >> 4) & 3;
  const int pq = g >> 6;
  const int q = pq & (KC - 1), p = pq >> 5;
  const int rr = p * 16 + l;          // logical row (k index of M's B-side)
  const int cc = q * 32 + h * 8;      // reduction col (e index)
  ushort hh[8], ll[8];
#pragma unroll
  for (int e = 0; e < 8; ++e) {
    const float v = in[(size_t)(cc + e) * 1024 + rr];
    hh[e] = f2bf(v);
    ll[e] = f2bf(v - bf2f(hh[e]));
  }
  *(uint4*)&hi[(size_t)g * 8] = *(const uint4*)hh;
  *(uint4*)&lo[(size_t)g * 8] = *(const uint4*)ll;
}

// ---------------------------------------------------------------------------
// ONE conversion launch: x (4096 blocks) + wo/wjv^T/wj (512 each), plus
// zeroing sc_raw and zsum (first 64 blocks).
// ---------------------------------------------------------------------------
__global__ __launch_bounds__(256) void cvt_all(
    const float* __restrict__ x, const float* __restrict__ wo,
    const float* __restrict__ wjv, const float* __restrict__ wj,
    ushort* __restrict__ xh, ushort* __restrict__ xl,
    ushort* __restrict__ woh, ushort* __restrict__ wol,
    ushort* __restrict__ wjvh, ushort* __restrict__ wjvl,
    ushort* __restrict__ wjh, ushort* __restrict__ wjl,
    float* __restrict__ sc_raw, float* __restrict__ zsum)
{
  const int blk = blockIdx.x;
  const int tid = threadIdx.x;
  if (blk < 64) {
    const int idx = blk * 256 + tid;          // 16384 = 2*R_ROWS floats
    if (idx < R_ROWS) sc_raw[idx] = 0.f;
    else              zsum[idx - R_ROWS] = 0.f;
  }
  if (blk < 4096) {
    split_frag_unit(x, xh, xl, blk * 256 + tid);
  } else if (blk < 4608) {
    split_frag_unit(wo, woh, wol, (blk - 4096) * 256 + tid);
  } else if (blk < 5120) {
    splitT_frag_unit(wjv, wjvh, wjvl, (blk - 4608) * 256 + tid);
  } else {
    split_frag_unit(wj, wjh, wjl, (blk - 5120) * 256 + tid);
  }
}

// ---------------------------------------------------------------------------
// MERGED: gemm_sq (blocks 0..511) + gemm_m (blocks 512..767).  NOW with
// sched_barrier(0)-pinned prefetch issue (round-12 PMC: VGPR=120 showed the
// compiler had de-pipelined the source dbuf, same as round-11 attn).
// ---------------------------------------------------------------------------
struct Frags { short8 ah[4], al[4], bh[4], bl[4]; };
struct Frags2 { short8 ah[2], al[2], bh[2], bl[2]; };

__global__ __launch_bounds__(256, 2) void gemm_sq_m(
    const ushort* __restrict__ xh, const ushort* __restrict__ xl,
    const ushort* __restrict__ wh, const ushort* __restrict__ wl,
    float* __restrict__ sc_raw,
    const ushort* __restrict__ ah_, const ushort* __restrict__ al_,
    const ushort* __restrict__ bh_, const ushort* __restrict__ bl_,
    ushort* __restrict__ Mf)
{
  const int blk = blockIdx.x;
  const int tid = threadIdx.x;
  const int wave = tid >> 6, lane = tid & 63;
  const int l15 = lane & 15, lq = lane >> 4;

  if (blk < 512) {
    // ---------------- gemm_sq path: sc_raw[r] = ||x_r @ wj^T||^2 ----------
    const int m0 = (blk >> 3) * 128, n0 = (blk & 7) * 128;
    const int wm = (wave & 1) * 64, wn = (wave >> 1) * 64;

    size_t aoff[4], boff[4];
#pragma unroll
    for (int i = 0; i < 4; ++i)
      aoff[i] = ((size_t)(((m0 + wm) >> 4) + i) * KC * 4 + lq) * 128 + l15 * 8;
#pragma unroll
    for (int j = 0; j < 4; ++j)
      boff[j] = ((size_t)(((n0 + wn) >> 4) + j) * KC * 4 + lq) * 128 + l15 * 8;

    f32x4 acc[4][4] = {};
    Frags f0, f1;

    auto load = [&](Frags& f, int q) {
      const size_t dq = (size_t)q * 512;
#pragma unroll
      for (int i = 0; i < 4; ++i) {
        f.ah[i] = *(const short8*)(xh + aoff[i] + dq);
        f.al[i] = *(const short8*)(xl + aoff[i] + dq);
      }
#pragma unroll
      for (int j = 0; j < 4; ++j) {
        f.bh[j] = *(const short8*)(wh + boff[j] + dq);
        f.bl[j] = *(const short8*)(wl + boff[j] + dq);
      }
    };
    auto step = [&](const Frags& f) {
#pragma unroll
      for (int i = 0; i < 4; ++i)
#pragma unroll
        for (int j = 0; j < 4; ++j) {
          acc[i][j] = __builtin_amdgcn_mfma_f32_16x16x32_bf16(f.ah[i], f.bh[j], acc[i][j], 0, 0, 0);
          acc[i][j] = __builtin_amdgcn_mfma_f32_16x16x32_bf16(f.ah[i], f.bl[j], acc[i][j], 0, 0, 0);
          acc[i][j] = __builtin_amdgcn_mfma_f32_16x16x32_bf16(f.al[i], f.bh[j], acc[i][j], 0, 0, 0);
        }
    };

    load(f0, 0);
    __builtin_amdgcn_sched_barrier(0);
#pragma unroll 1
    for (int q = 0; q < KC; q += 2) {
      load(f1, q + 1);
      __builtin_amdgcn_sched_barrier(0);   // f1 loads ISSUE before f0's MFMAs
      step(f0);
      if (q + 2 < KC) {
        load(f0, q + 2);
        __builtin_amdgcn_sched_barrier(0); // f0 loads ISSUE before f1's MFMAs
      }
      step(f1);
    }

    __shared__ float red[128][33];
#pragma unroll
    for (int i = 0; i < 4; ++i)
#pragma unroll
      for (int r = 0; r < 4; ++r) {
        const int row = wm + i * 16 + lq * 4 + r;
        float s = 0.f;
#pragma unroll
        for (int j = 0; j < 4; ++j) s += acc[i][j][r] * acc[i][j][r];
        red[row][(l15 << 1) | (wave >> 1)] = s;
      }
    __syncthreads();
    if (tid < 128) {
      float s = 0.f;
#pragma unroll
      for (int c = 0; c < 32; ++c) s += red[tid][c];
      atomicAdd(&sc_raw[m0 + tid], s);
    }
  } else {
    // ---------------- gemm_m path: Mf = bf16(wo @ wjv) in frag layout ------
    const int mm = blk - 512;
    const int m0 = (mm >> 4) * 64, n0 = (mm & 15) * 64;
    const int wm = (wave & 1) * 32, wn = (wave >> 1) * 32;

    size_t aoff[2], boff[2];
#pragma unroll
    for (int i = 0; i < 2; ++i)
      aoff[i] = ((size_t)(((m0 + wm) >> 4) + i) * KC * 4 + lq) * 128 + l15 * 8;
#pragma unroll
    for (int j = 0; j < 2; ++j)
      boff[j] = ((size_t)(((n0 + wn) >> 4) + j) * KC * 4 + lq) * 128 + l15 * 8;

    f32x4 acc[2][2] = {};
    Frags2 f0, f1;

    auto load = [&](Frags2& f, int q) {
      const size_t dq = (size_t)q * 512;
#pragma unroll
      for (int i = 0; i < 2; ++i) {
        f.ah[i] = *(const short8*)(ah_ + aoff[i] + dq);
        f.al[i] = *(const short8*)(al_ + aoff[i] + dq);
      }
#pragma unroll
      for (int j = 0; j < 2; ++j) {
        f.bh[j] = *(const short8*)(bh_ + boff[j] + dq);
        f.bl[j] = *(const short8*)(bl_ + boff[j] + dq);
      }
    };
    auto step = [&](const Frags2& f) {
#pragma unroll
      for (int i = 0; i < 2; ++i)
#pragma unroll
        for (int j = 0; j < 2; ++j) {
          acc[i][j] = __builtin_amdgcn_mfma_f32_16x16x32_bf16(f.ah[i], f.bh[j], acc[i][j], 0, 0, 0);
          acc[i][j] = __builtin_amdgcn_mfma_f32_16x16x32_bf16(f.ah[i], f.bl[j], acc[i][j], 0, 0, 0);
          acc[i][j] = __builtin_amdgcn_mfma_f32_16x16x32_bf16(f.al[i], f.bh[j], acc[i][j], 0, 0, 0);
        }
    };

    load(f0, 0);
    __builtin_amdgcn_sched_barrier(0);
#pragma unroll 1
    for (int q = 0; q < KC; q += 2) {
      load(f1, q + 1);
      __builtin_amdgcn_sched_barrier(0);
      step(f0);
      if (q + 2 < KC) {
        load(f0, q + 2);
        __builtin_amdgcn_sched_barrier(0);
      }
      step(f1);
    }

#pragma unroll
    for (int i = 0; i < 2; ++i)
#pragma unroll
      for (int j = 0; j < 2; ++j) {
        const int fb = m0 + wm + i * 16 + lq * 4;
        const int k  = n0 + wn + j * 16 + l15;
#pragma unroll
        for (int r = 0; r < 4; ++r) {
          const int f = fb + r;
          const size_t addr =
              (((size_t)(f >> 4) * KC + (k >> 5)) * 4 + ((k >> 3) & 3)) * 128 +
              (f & 15) * 8 + (k & 7);
          Mf[addr] = f2bf(acc[i][j][r]);
        }
      }
  }
}

// ---------------------------------------------------------------------------
// P generation + prefix-max + softmax denominator, ONE kernel.
// Grid (8, 4, 16) = 512 blocks (2/CU).
// ---------------------------------------------------------------------------
__global__ __launch_bounds__(512) void pgen2(
    const float* __restrict__ sc_raw, ushort* __restrict__ P012,
    ushort* __restrict__ P3, float* __restrict__ zsum)
{
  const int y = blockIdx.x, b = blockIdx.y, zslice = blockIdx.z;
  const int bT = b * T_SEQ;
  ushort* pb = (b < 3) ? P012 + (size_t)b * PBATCH_ELEMS : P3;
  __shared__ float scs[T_SEQ];
  __shared__ float pma[T_SEQ];
  __shared__ float pmb[T_SEQ];
  const int tid = threadIdx.x;
  for (int i = tid; i < T_SEQ; i += 512) {
    const float v = sc_raw[bT + i] * 0.03125f;
    scs[i] = v;
    pma[i] = v;
  }
  __syncthreads();
  float* src = pma; float* dst = pmb;
  for (int off = 1; off < T_SEQ; off <<= 1) {
    for (int i = tid; i < T_SEQ; i += 512)
      dst[i] = (i >= off) ? fmaxf(src[i], src[i - off]) : src[i];
    __syncthreads();
    float* t = src; src = dst; dst = t;
  }
  const float* pms = src;   // inclusive prefix max

  const int lane = tid & 63;
  const int hi = lane >> 4, l = lane & 15;

#pragma unroll 1
  for (int ph = 0; ph < 2; ++ph) {
    const int P = ph ? y : 15 - y;
    const int W = 4 * P + 4;
    ushort* base = pb + (size_t)(16 * P * (P + 1)) * 512;
    const int nu = 512 * W;   // 16B units in this supertile
#pragma unroll 1
    for (int u = tid + zslice * 512; u < nu; u += 8192) {
      const int pr = (u >> 6) & 7, q = u >> 9;
      const int t = P * 128 + pr * 16 + l;
      const int s0 = q * 32 + hi * 8;
      const float st = scs[t], pm = pms[t];
      ushort tmp[8];
      float z = 0.f;
#pragma unroll
      for (int e = 0; e < 8; ++e) {
        const int s = s0 + e;
        float pe = 0.f;
        if (s <= t) pe = __expf(st * (scs[s] - pm));
        tmp[e] = f2bf(pe);
        z += pe;
      }
      *(uint4*)&base[(size_t)(pr * W + q) * 512 + hi * 128 + l * 8] =
          *(const uint4*)tmp;
      // reduce the 4 hi-lanes that share row t, one atomic per row
      z += __shfl_xor(z, 16);
      z += __shfl_xor(z, 32);
      if (hi == 0) atomicAdd(&zsum[bT + t], z);
    }
  }
}

// ---------------------------------------------------------------------------
// WT[f][rg] = sum_k M[f][k]*x[rg][k], 2-chunk double-buffer with
// sched_barrier(0)-pinned prefetch issue (round-12 win, unchanged).
// ---------------------------------------------------------------------------
struct FP2 { short8 a[2][4]; short8 b[2][4]; };

__global__ __launch_bounds__(256, 2) void gemm_wt(
    const ushort* __restrict__ Af, const ushort* __restrict__ Bf,
    ushort* __restrict__ WT)
{
  const int tid = threadIdx.x;
  const int m0 = blockIdx.y * 128, n0 = blockIdx.x * 128;
  const int wave = tid >> 6, lane = tid & 63;
  const int l15 = lane & 15, lq = lane >> 4;
  const int wm = (wave & 1) * 64, wn = (wave >> 1) * 64;

  size_t aoff[4], boff[4];
#pragma unroll
  for (int i = 0; i < 4; ++i)
    aoff[i] = ((size_t)(((m0 + wm) >> 4) + i) * KC * 4 + lq) * 128 + l15 * 8;
#pragma unroll
  for (int j = 0; j < 4; ++j)
    boff[j] = ((size_t)(((n0 + wn) >> 4) + j) * KC * 4 + lq) * 128 + l15 * 8;

  f32x4 acc[4][4] = {};
  FP2 f0, f1;

  auto load2 = [&](FP2& f, int q) {
#pragma unroll
    for (int c = 0; c < 2; ++c) {
      const size_t dq = (size_t)(q + c) * 512;
#pragma unroll
      for (int i = 0; i < 4; ++i) f.a[c][i] = *(const short8*)(Af + aoff[i] + dq);
#pragma unroll
      for (int j = 0; j < 4; ++j) f.b[c][j] = *(const short8*)(Bf + boff[j] + dq);
    }
  };
  auto step2 = [&](const FP2& f) {
#pragma unroll
    for (int c = 0; c < 2; ++c)
#pragma unroll
      for (int i = 0; i < 4; ++i)
#pragma unroll
        for (int j = 0; j < 4; ++j)
          acc[i][j] = __builtin_amdgcn_mfma_f32_16x16x32_bf16(f.a[c][i], f.b[c][j], acc[i][j], 0, 0, 0);
  };

  load2(f0, 0);
  __builtin_amdgcn_sched_barrier(0);
#pragma unroll 1
  for (int q = 0; q < KC; q += 4) {
    load2(f1, q + 2);
    __builtin_amdgcn_sched_barrier(0);   // f1 loads ISSUE before f0's MFMAs
    step2(f0);
    if (q + 4 < KC) {
      load2(f0, q + 4);
      __builtin_amdgcn_sched_barrier(0); // f0 loads ISSUE before f1's MFMAs
    }
    step2(f1);
  }

#pragma unroll
  for (int i = 0; i < 4; ++i)
#pragma unroll
    for (int j = 0; j < 4; ++j) {
      const int eb = m0 + wm + i * 16 + lq * 4;
      const int rg = n0 + wn + j * 16 + l15;
#pragma unroll
      for (int r = 0; r < 4; ++r) {
        const int e = eb + r;
        const size_t addr =
            (((size_t)(e >> 4) * KCR + (rg >> 5)) * 4 + ((rg >> 3) & 3)) * 128 +
            (e & 15) * 8 + (rg & 7);
        WT[addr] = f2bf(acc[i][j][r]);
      }
    }
}

// ---------------------------------------------------------------------------
// Attention GEMM: paired supertiles (15-y, y), 512 thr / 8 waves (2t x 4e),
// 2-chunk double-buffer with sched_barrier(0)-pinned prefetch (round-12 win).
//   out[t][e] = (1/zsum[t]) * sum_s P[t][s] * W[s][e]
// ---------------------------------------------------------------------------
struct FA2 { short8 a[2][4]; short8 b[2][2]; };

__global__ __launch_bounds__(512) void attn_gemm(
    const ushort* __restrict__ P012, const ushort* __restrict__ P3,
    const ushort* __restrict__ WT, const float* __restrict__ zsum,
    float* __restrict__ outp)
{
  const int b = blockIdx.z, y = blockIdx.y;
  const int e0 = blockIdx.x * 128;
  const int bT = b * T_SEQ;
  const ushort* pb = (b < 3) ? P012 + (size_t)b * PBATCH_ELEMS : P3;
  const int tid = threadIdx.x;
  const int wave = tid >> 6, lane = tid & 63;
  const int l15 = lane & 15, lq = lane >> 4;
  const int wm = (wave & 1) * 64;       // t-offset within 128
  const int wn = (wave >> 1) * 32;      // e-offset within 128

  size_t boff[2];
#pragma unroll
  for (int j = 0; j < 2; ++j)
    boff[j] = ((size_t)((((e0 + wn) >> 4) + j) * KCR + (bT >> 5)) * 4 + lq) * 128
              + l15 * 8;

#pragma unroll 1
  for (int ph = 0; ph < 2; ++ph) {
    const int ty = ph ? y : 15 - y;
    const int W = 4 * ty + 4;           // multiple of 4
    const int t0 = ty * 128;

    size_t aoff[4];
#pragma unroll
    for (int i = 0; i < 4; ++i)
      aoff[i] = ((size_t)(16 * ty * (ty + 1)) + (size_t)((wm >> 4) + i) * W) * 512
                + lq * 128 + l15 * 8;

    f32x4 acc[4][2] = {};
    FA2 f0, f1;

    auto load2 = [&](FA2& f, int q) {
#pragma unroll
      for (int c = 0; c < 2; ++c) {
        const size_t dq = (size_t)(q + c) * 512;
#pragma unroll
        for (int i = 0; i < 4; ++i) f.a[c][i] = *(const short8*)(pb + aoff[i] + dq);
#pragma unroll
        for (int j = 0; j < 2; ++j) f.b[c][j] = *(const short8*)(WT + boff[j] + dq);
      }
    };
    auto step2 = [&](const FA2& f) {
#pragma unroll
      for (int c = 0; c < 2; ++c)
#pragma unroll
        for (int i = 0; i < 4; ++i)
#pragma unroll
          for (int j = 0; j < 2; ++j)
            acc[i][j] = __builtin_amdgcn_mfma_f32_16x16x32_bf16(
                f.a[c][i], f.b[c][j], acc[i][j], 0, 0, 0);
    };

    load2(f0, 0);
    __builtin_amdgcn_sched_barrier(0);
#pragma unroll 1
    for (int q = 0; q < W; q += 4) {
      load2(f1, q + 2);
      __builtin_amdgcn_sched_barrier(0);   // pin f1 issue before f0 MFMAs
      step2(f0);
      if (q + 4 < W) {
        load2(f0, q + 4);
        __builtin_amdgcn_sched_barrier(0); // pin f0 issue before f1 MFMAs
      }
      step2(f1);
    }

    // Epilogue: scale by 1/zsum, write fp32 final output.
#pragma unroll
    for (int i = 0; i < 4; ++i)
#pragma unroll
      for (int r = 0; r < 4; ++r) {
        const int row = t0 + wm + i * 16 + lq * 4 + r;
        const float zi = 1.0f / zsum[bT + row];
#pragma unroll
        for (int j = 0; j < 2; ++j) {
          const int nb = e0 + wn + j * 16 + l15;
          outp[(size_t)(bT + row) * E_DIM + nb] = acc[i][j][r] * zi;
        }
      }
  }
}

// ---------------------------------------------------------------------------
extern "C" void kernel_launch(void* const* d_in, const int* in_sizes, int n_in,
                              void* d_out, int out_size, void* d_ws, size_t ws_size,
                              hipStream_t stream) {
  (void)in_sizes; (void)n_in; (void)out_size; (void)ws_size;
  const float* x   = (const float*)d_in[0];
  const float* wj  = (const float*)d_in[1];
  const float* wjv = (const float*)d_in[2];
  const float* wo  = (const float*)d_in[3];
  float* out = (float*)d_out;

  ushort* xh_f  = (ushort*)d_ws;                        // 16.8 MB; later P(b0..2)
  ushort* xl_f  = xh_f  + (size_t)R_ROWS * E_DIM;       // 16.8 MB; later WT
  ushort* woh   = xl_f  + (size_t)R_ROWS * E_DIM;       // 2 MB, dead after gemm_sq_m
  ushort* wol   = woh   + (size_t)E_DIM * E_DIM;        // 2 MB
  ushort* wjvh  = wol   + (size_t)E_DIM * E_DIM;        // 2 MB
  ushort* wjvl  = wjvh  + (size_t)E_DIM * E_DIM;        // 2 MB
  ushort* wjh   = wjvl  + (size_t)E_DIM * E_DIM;        // 2 MB
  ushort* wjl   = wjh   + (size_t)E_DIM * E_DIM;        // 2 MB
  ushort* Mf    = wjl   + (size_t)E_DIM * E_DIM;        // 2 MB: bf16 M frags
  float* sc_raw = (float*)(Mf + (size_t)E_DIM * E_DIM);
  float* zsum   = sc_raw + R_ROWS;
  ushort* WT    = xl_f;     // xl_f dead after gemm_sq_m (stream-serial)
  ushort* P012  = xh_f;     // xh_f dead after gemm_wt (3 x 4.46 MB <= 16.8 MB)
  ushort* P3    = woh;      // woh..wjl (12 MB) dead after gemm_sq_m

  // 1) all conversions + zero sc_raw/zsum (one launch)
  cvt_all<<<5632, 256, 0, stream>>>(x, wo, wjv, wj,
                                    xh_f, xl_f, woh, wol, wjvh, wjvl, wjh, wjl,
                                    sc_raw, zsum);

  // 2) MERGED: sc_raw[r] = ||x_r @ wj^T||^2  AND  Mf = bf16(wo @ wjv)
  //    (now sched_barrier-pinned prefetch in both paths)
  gemm_sq_m<<<768, 256, 0, stream>>>(xh_f, xl_f, wjh, wjl, sc_raw,
                                     woh, wol, wjvh, wjvl, Mf);

  // 3) WT[f][rg] = sum_k M[f][k]*x[rg][k]  (pinned prefetch)
  gemm_wt<<<dim3(R_ROWS/128, E_DIM/128), 256, 0, stream>>>(Mf, xh_f, WT);

  // 4) P (packed frags) + prefix-max + zsum
  pgen2<<<dim3(8, 4, 16), 512, 0, stream>>>(sc_raw, P012, P3, zsum);

  // 5) out[t][e] = zinv[t] * sum_s P[t][s] * W[s][e]  (pinned prefetch)
  attn_gemm<<<dim3(E_DIM/128, 8, 4), 512, 0, stream>>>(P012, P3, WT, zsum, out);
}